// Round 3
// baseline (692.630 us; speedup 1.0000x reference)
//
#include <hip/hip_runtime.h>

#define RES   512
#define NCH   64            // channels
#define SP    (RES * RES)   // 262144 texels per plane

// Morton binning for point sort (3D locality => locality in all 3 plane projections)
#define NBITS 5
#define NSIDE (1 << NBITS)           // 32 voxels per axis
#define NBINS (1 << (3 * NBITS))     // 32768 bins, ~32 pts/bin at 1M pts

#define TRBLK 3072                   // transpose blocks: 3 * (SP/256)

typedef float v4f __attribute__((ext_vector_type(4)));

__device__ __forceinline__ v4f nt_load4(const float* p)
{
    return __builtin_nontemporal_load((const v4f*)p);
}
__device__ __forceinline__ void nt_store4(float* p, v4f v)
{
    __builtin_nontemporal_store(v, (v4f*)p);
}

// ---------------------------------------------------------------------------
// Morton helpers
// ---------------------------------------------------------------------------
__device__ __forceinline__ unsigned part1by2(unsigned v)
{
    v &= 0x3FF;
    v = (v | (v << 16)) & 0x030000FF;
    v = (v | (v <<  8)) & 0x0300F00F;
    v = (v | (v <<  4)) & 0x030C30C3;
    v = (v | (v <<  2)) & 0x09249249;
    return v;
}

__device__ __forceinline__ unsigned bin_of(float x, float y, float z)
{
    int ix = (int)((x + 1.0f) * 0.5f * (float)NSIDE);
    int iy = (int)((y + 1.0f) * 0.5f * (float)NSIDE);
    int iz = (int)((z + 1.0f) * 0.5f * (float)NSIDE);
    ix = min(max(ix, 0), NSIDE - 1);
    iy = min(max(iy, 0), NSIDE - 1);
    iz = min(max(iz, 0), NSIDE - 1);
    return part1by2((unsigned)ix) | (part1by2((unsigned)iy) << 1)
         | (part1by2((unsigned)iz) << 2);
}

// ---------------------------------------------------------------------------
// Kernel H: histogram of Morton bins (exposed, ~15-20 us; scatter is hidden
// under the transpose instead because scatter depends on the scan).
// ---------------------------------------------------------------------------
__global__ __launch_bounds__(256) void hist_kernel(
    const float* __restrict__ pts, unsigned* __restrict__ hist, int npts)
{
    int i = blockIdx.x * 256 + threadIdx.x;
    if (i >= npts) return;
    float x = pts[3 * (size_t)i + 0];
    float y = pts[3 * (size_t)i + 1];
    float z = pts[3 * (size_t)i + 2];
    atomicAdd(&hist[bin_of(x, y, z)], 1u);
}

// ---------------------------------------------------------------------------
// Kernel S2: exclusive prefix sum over 32768 bins (single block, 1024 thr)
// ---------------------------------------------------------------------------
__global__ __launch_bounds__(1024) void scan_kernel(
    const unsigned* __restrict__ hist, unsigned* __restrict__ offs)
{
    __shared__ unsigned partial[1024];
    int t = threadIdx.x;
    unsigned base = (unsigned)t * 32;
    unsigned local[32];
    unsigned s = 0;
    #pragma unroll
    for (int k = 0; k < 32; ++k) { local[k] = s; s += hist[base + k]; }
    partial[t] = s;
    __syncthreads();
    for (int d = 1; d < 1024; d <<= 1) {
        unsigned v = (t >= d) ? partial[t - d] : 0u;
        __syncthreads();
        partial[t] += v;
        __syncthreads();
    }
    unsigned chunk_excl = (t == 0) ? 0u : partial[t - 1];
    #pragma unroll
    for (int k = 0; k < 32; ++k) offs[base + k] = chunk_excl + local[k];
}

// ---------------------------------------------------------------------------
// Kernel 1 (fused): blocks [0, TRBLK) transpose planes (3,C,R,R)->(3,R*R,C);
// blocks [TRBLK, ...) scatter points into Morton order (hidden under transpose;
// scatter needs the scan result, which is why hist runs separately before).
//
// Transpose: 64ch x 256sp per block via two 32x257 half-tiles (32.9 KB LDS,
// 4 blocks/CU). Per-channel global reads are now 1 KB contiguous (round-2
// theory: 512 B streams = ~50% DRAM row utilization = the measured 2.1 TB/s).
// Phase-B loads are issued before phase-A stores to hide their latency.
// Writes are full 128 B lines (ch 0-31 / 32-63 of each texel, merged in L2).
// nt loads: one-shot stream must not thrash L2/L3; tp writes stay cached.
// ---------------------------------------------------------------------------
__global__ __launch_bounds__(256) void transpose_scatter(
    const float* __restrict__ in, float* __restrict__ out,
    const float* __restrict__ pts, unsigned* __restrict__ offs,
    float* __restrict__ spts4, int npts)
{
    __shared__ float tile[32][257];   // 257: (ch + sp) bank spread, <=2-way

    int b = blockIdx.x;
    if (b >= TRBLK) {
        int i = (b - TRBLK) * 256 + threadIdx.x;
        if (i < npts) {
            float x = pts[3 * (size_t)i + 0];
            float y = pts[3 * (size_t)i + 1];
            float z = pts[3 * (size_t)i + 2];
            unsigned pos = atomicAdd(&offs[bin_of(x, y, z)], 1u);
            v4f v;
            v[0] = x; v[1] = y; v[2] = z; v[3] = __uint_as_float((unsigned)i);
            *(v4f*)(spts4 + 4 * (size_t)pos) = v;
        }
        return;
    }

    int plane = b >> 10;              // 1024 tiles per plane
    int s0    = (b & 1023) << 8;      // * 256 spatial base
    const float* src = in  + (size_t)plane * NCH * SP;
    float*       dst = out + (size_t)plane * SP  * NCH;

    int t   = threadIdx.x;
    int lch = t >> 3;                 // load: channel 0..31 (within half)
    int lsp = (t & 7) << 2;           // load: spatial float4 base 0,4,..,28
    int sch = (t & 7) << 2;           // store: channel group 0,4,..,28
    int ssp = t >> 3;                 // store: spatial base 0..31

    v4f ra[8], rb[8];

    // phase A global loads: channels 0..31, 1 KB contiguous per channel/block
    #pragma unroll
    for (int i = 0; i < 8; ++i)
        ra[i] = nt_load4(src + (size_t)lch * SP + s0 + lsp + i * 32);
    #pragma unroll
    for (int i = 0; i < 8; ++i) {
        int sp = lsp + i * 32;
        tile[lch][sp + 0] = ra[i][0];
        tile[lch][sp + 1] = ra[i][1];
        tile[lch][sp + 2] = ra[i][2];
        tile[lch][sp + 3] = ra[i][3];
    }
    __syncthreads();

    // phase B global loads issued EARLY (latency hides under phase-A stores)
    #pragma unroll
    for (int i = 0; i < 8; ++i)
        rb[i] = nt_load4(src + (size_t)(lch + 32) * SP + s0 + lsp + i * 32);

    // phase A stores: out[(s0+s)*64 + 0..31] — full 128 B lines
    #pragma unroll
    for (int j = 0; j < 8; ++j) {
        int s = ssp + j * 32;
        v4f v;
        v[0] = tile[sch + 0][s];
        v[1] = tile[sch + 1][s];
        v[2] = tile[sch + 2][s];
        v[3] = tile[sch + 3][s];
        *(v4f*)(dst + (size_t)(s0 + s) * NCH + sch) = v;
    }
    __syncthreads();

    #pragma unroll
    for (int i = 0; i < 8; ++i) {
        int sp = lsp + i * 32;
        tile[lch][sp + 0] = rb[i][0];
        tile[lch][sp + 1] = rb[i][1];
        tile[lch][sp + 2] = rb[i][2];
        tile[lch][sp + 3] = rb[i][3];
    }
    __syncthreads();

    // phase B stores: out[(s0+s)*64 + 32..63]
    #pragma unroll
    for (int j = 0; j < 8; ++j) {
        int s = ssp + j * 32;
        v4f v;
        v[0] = tile[sch + 0][s];
        v[1] = tile[sch + 1][s];
        v[2] = tile[sch + 2][s];
        v[3] = tile[sch + 3][s];
        *(v4f*)(dst + (size_t)(s0 + s) * NCH + 32 + sch) = v;
    }
}

// ---------------------------------------------------------------------------
// Kernel 2 (sorted): gather from texel-major planes in Morton order.
// 16 threads per point, float4 of channels each; texel access = 256 B/16 lanes.
// NT stores for out (streaming 262 MB must not evict cached planes);
// NT load for spts4 (one-shot). Chunked bijective XCD swizzle.
// ---------------------------------------------------------------------------
__global__ __launch_bounds__(256) void gather_sorted(
    const float* __restrict__ spts4,
    const float* __restrict__ tp, float* __restrict__ out,
    int npts, int nblk)
{
    int cpx = nblk >> 3;                       // nblk % 8 == 0 by launch
    int b   = blockIdx.x;
    int swz = (b & 7) * cpx + (b >> 3);        // bijective chunked XCD swizzle
    int t   = swz * 256 + threadIdx.x;
    int j   = t >> 4;                          // sorted position
    if (j >= npts) return;
    int cg  = (t & 15) << 2;                   // channel offset 0..60

    v4f s = nt_load4(spts4 + 4 * (size_t)j);   // broadcast within group
    float px = s[0], py = s[1], pz = s[2];
    unsigned idx = __float_as_uint(s[3]);

    float us[3] = {px, px, py};
    float vs[3] = {py, pz, pz};

    v4f acc = {0.f, 0.f, 0.f, 0.f};

    #pragma unroll
    for (int pl = 0; pl < 3; ++pl) {
        float fx = fminf(fmaxf((us[pl] + 1.0f) * 0.5f * 511.0f, 0.0f), 511.0f);
        float fy = fminf(fmaxf((vs[pl] + 1.0f) * 0.5f * 511.0f, 0.0f), 511.0f);
        float x0f = floorf(fx), y0f = floorf(fy);
        int   x0  = (int)x0f,  y0  = (int)y0f;
        float wx  = fx - x0f,  wy  = fy - y0f;
        int   x1  = min(x0 + 1, RES - 1);
        int   y1  = min(y0 + 1, RES - 1);

        const float* base = tp + (size_t)pl * SP * NCH;
        v4f v00 = *(const v4f*)(base + ((size_t)(y0 * RES + x0) * NCH) + cg);
        v4f v01 = *(const v4f*)(base + ((size_t)(y0 * RES + x1) * NCH) + cg);
        v4f v10 = *(const v4f*)(base + ((size_t)(y1 * RES + x0) * NCH) + cg);
        v4f v11 = *(const v4f*)(base + ((size_t)(y1 * RES + x1) * NCH) + cg);

        float w00 = (1.0f - wx) * (1.0f - wy);
        float w01 = wx * (1.0f - wy);
        float w10 = (1.0f - wx) * wy;
        float w11 = wx * wy;

        acc += w00 * v00 + w01 * v01 + w10 * v10 + w11 * v11;
    }

    nt_store4(out + (size_t)idx * NCH + cg, acc);
}

// ---------------------------------------------------------------------------
// Fallback tier: unsorted gather from texel-major planes.
// ---------------------------------------------------------------------------
__global__ __launch_bounds__(256) void gather_tp(
    const float* __restrict__ pts,
    const float* __restrict__ tp,
    float* __restrict__ out, int npts)
{
    int t  = blockIdx.x * 256 + threadIdx.x;
    int pt = t >> 4;
    if (pt >= npts) return;
    int cg = (t & 15) << 2;

    float px = pts[3 * (size_t)pt + 0];
    float py = pts[3 * (size_t)pt + 1];
    float pz = pts[3 * (size_t)pt + 2];

    float us[3] = {px, px, py};
    float vs[3] = {py, pz, pz};

    v4f acc = {0.f, 0.f, 0.f, 0.f};

    #pragma unroll
    for (int pl = 0; pl < 3; ++pl) {
        float fx = fminf(fmaxf((us[pl] + 1.0f) * 0.5f * 511.0f, 0.0f), 511.0f);
        float fy = fminf(fmaxf((vs[pl] + 1.0f) * 0.5f * 511.0f, 0.0f), 511.0f);
        float x0f = floorf(fx), y0f = floorf(fy);
        int   x0  = (int)x0f,  y0  = (int)y0f;
        float wx  = fx - x0f,  wy  = fy - y0f;
        int   x1  = min(x0 + 1, RES - 1);
        int   y1  = min(y0 + 1, RES - 1);

        const float* base = tp + (size_t)pl * SP * NCH;
        v4f v00 = *(const v4f*)(base + ((size_t)(y0 * RES + x0) * NCH) + cg);
        v4f v01 = *(const v4f*)(base + ((size_t)(y0 * RES + x1) * NCH) + cg);
        v4f v10 = *(const v4f*)(base + ((size_t)(y1 * RES + x0) * NCH) + cg);
        v4f v11 = *(const v4f*)(base + ((size_t)(y1 * RES + x1) * NCH) + cg);

        float w00 = (1.0f - wx) * (1.0f - wy);
        float w01 = wx * (1.0f - wy);
        float w10 = (1.0f - wx) * wy;
        float w11 = wx * wy;

        acc += w00 * v00 + w01 * v01 + w10 * v10 + w11 * v11;
    }

    *(v4f*)(out + (size_t)pt * NCH + cg) = acc;
}

// ---------------------------------------------------------------------------
// Last-resort fallback: direct gather from original (3, C, R, R) layout.
// ---------------------------------------------------------------------------
__global__ __launch_bounds__(256) void gather_direct(
    const float* __restrict__ pts,
    const float* __restrict__ planes,
    float* __restrict__ out, int npts)
{
    long t = (long)blockIdx.x * 256 + threadIdx.x;
    int pt = (int)(t >> 6);
    if (pt >= npts) return;
    int ch = (int)(t & 63);

    float px = pts[3 * (size_t)pt + 0];
    float py = pts[3 * (size_t)pt + 1];
    float pz = pts[3 * (size_t)pt + 2];
    float us[3] = {px, px, py};
    float vs[3] = {py, pz, pz};

    float acc = 0.0f;
    #pragma unroll
    for (int pl = 0; pl < 3; ++pl) {
        float fx = fminf(fmaxf((us[pl] + 1.0f) * 0.5f * 511.0f, 0.0f), 511.0f);
        float fy = fminf(fmaxf((vs[pl] + 1.0f) * 0.5f * 511.0f, 0.0f), 511.0f);
        float x0f = floorf(fx), y0f = floorf(fy);
        int   x0  = (int)x0f,  y0  = (int)y0f;
        float wx  = fx - x0f,  wy  = fy - y0f;
        int   x1  = min(x0 + 1, RES - 1);
        int   y1  = min(y0 + 1, RES - 1);

        const float* base = planes + (size_t)pl * NCH * SP + (size_t)ch * SP;
        float v00 = base[y0 * RES + x0];
        float v01 = base[y0 * RES + x1];
        float v10 = base[y1 * RES + x0];
        float v11 = base[y1 * RES + x1];

        acc += v00 * ((1.0f - wx) * (1.0f - wy))
             + v01 * (wx * (1.0f - wy))
             + v10 * ((1.0f - wx) * wy)
             + v11 * (wx * wy);
    }
    out[(size_t)pt * NCH + ch] = acc;
}

extern "C" void kernel_launch(void* const* d_in, const int* in_sizes, int n_in,
                              void* d_out, int out_size, void* d_ws, size_t ws_size,
                              hipStream_t stream)
{
    (void)n_in; (void)out_size;
    const float* pts    = (const float*)d_in[0];
    const float* planes = (const float*)d_in[1];
    float*       out    = (float*)d_out;
    int npts = in_sizes[0] / 3;

    // workspace layout
    size_t sz_tp     = (size_t)3 * NCH * SP * sizeof(float);       // 201.3 MB
    size_t off_spts  = sz_tp;
    size_t sz_spts   = (size_t)npts * 4 * sizeof(float);           // float4/point
    size_t off_hist  = off_spts + sz_spts;
    size_t off_offs  = off_hist + (size_t)NBINS * sizeof(unsigned);
    size_t need_sort = off_offs + (size_t)NBINS * sizeof(unsigned);

    int nptblk = (npts + 255) / 256;

    if (ws_size >= need_sort) {
        float*    tp   = (float*)d_ws;
        float*    sp4  = (float*)((char*)d_ws + off_spts);
        unsigned* hist = (unsigned*)((char*)d_ws + off_hist);
        unsigned* offs = (unsigned*)((char*)d_ws + off_offs);

        hipMemsetAsync(hist, 0, (size_t)NBINS * sizeof(unsigned), stream);
        hist_kernel<<<nptblk, 256, 0, stream>>>(pts, hist, npts);
        scan_kernel<<<1, 1024, 0, stream>>>(hist, offs);
        transpose_scatter<<<TRBLK + nptblk, 256, 0, stream>>>(
            planes, tp, pts, offs, sp4, npts);

        long nthr = (long)npts * 16;
        int  nblk = (int)((nthr + 255) / 256);
        nblk = (nblk + 7) & ~7;                 // multiple of 8 for bijective swizzle
        gather_sorted<<<nblk, 256, 0, stream>>>(sp4, tp, out, npts, nblk);
    } else if (ws_size >= sz_tp) {
        transpose_scatter<<<TRBLK, 256, 0, stream>>>(
            planes, (float*)d_ws, nullptr, nullptr, nullptr, 0);
        long nthr = (long)npts * 16;
        gather_tp<<<(int)((nthr + 255) / 256), 256, 0, stream>>>(
            pts, (const float*)d_ws, out, npts);
    } else {
        long nthr = (long)npts * 64;
        gather_direct<<<(int)((nthr + 255) / 256), 256, 0, stream>>>(
            pts, planes, out, npts);
    }
}

// Round 4
// 609.109 us; speedup vs baseline: 1.1371x; 1.1371x over previous
//
#include <hip/hip_runtime.h>

#define RES   512
#define NCH   64            // channels
#define SP    (RES * RES)   // 262144 texels per plane

// Morton binning for point sort (3D locality => locality in all 3 plane projections)
#define NBITS 5
#define NSIDE (1 << NBITS)           // 32 voxels per axis
#define NBINS (1 << (3 * NBITS))     // 32768 bins, ~32 pts/bin at 1M pts

#define TRBLK 6144                   // transpose blocks: 3 * (SP/128)  [round-2 proven tile]

typedef float     v4f __attribute__((ext_vector_type(4)));
typedef _Float16  h4  __attribute__((ext_vector_type(4)));

__device__ __forceinline__ v4f nt_load4(const float* p)
{
    return __builtin_nontemporal_load((const v4f*)p);
}
__device__ __forceinline__ void nt_store4(float* p, v4f v)
{
    __builtin_nontemporal_store(v, (v4f*)p);
}

// ---------------------------------------------------------------------------
// Morton helpers
// ---------------------------------------------------------------------------
__device__ __forceinline__ unsigned part1by2(unsigned v)
{
    v &= 0x3FF;
    v = (v | (v << 16)) & 0x030000FF;
    v = (v | (v <<  8)) & 0x0300F00F;
    v = (v | (v <<  4)) & 0x030C30C3;
    v = (v | (v <<  2)) & 0x09249249;
    return v;
}

__device__ __forceinline__ unsigned bin_of(float x, float y, float z)
{
    int ix = (int)((x + 1.0f) * 0.5f * (float)NSIDE);
    int iy = (int)((y + 1.0f) * 0.5f * (float)NSIDE);
    int iz = (int)((z + 1.0f) * 0.5f * (float)NSIDE);
    ix = min(max(ix, 0), NSIDE - 1);
    iy = min(max(iy, 0), NSIDE - 1);
    iz = min(max(iz, 0), NSIDE - 1);
    return part1by2((unsigned)ix) | (part1by2((unsigned)iy) << 1)
         | (part1by2((unsigned)iz) << 2);
}

// ---------------------------------------------------------------------------
// Kernel 1 (fused, round-2 structure): blocks [0, TRBLK) transpose planes
// (3,C,R,R) fp32 -> (3,R*R,C) fp16; blocks [TRBLK,...) do the Morton histogram
// (hidden under the transpose). 64ch x 128sp tile, fp32 LDS [64][129] (33 KB,
// 4 blocks/CU). fp16 stores: 4 texel rows x 128 B = 512 B contiguous per wave
// instruction. nt loads: one-shot src stream must not thrash L2/L3.
// ---------------------------------------------------------------------------
__global__ __launch_bounds__(256) void transpose_hist(
    const float* __restrict__ in, _Float16* __restrict__ out,
    const float* __restrict__ pts, unsigned* __restrict__ hist, int npts)
{
    __shared__ float tile[64][129];   // 2-way bank alias max on column reads

    int b = blockIdx.x;
    if (b >= TRBLK) {
        int i = (b - TRBLK) * 256 + threadIdx.x;
        if (i < npts) {
            float x = pts[3 * (size_t)i + 0];
            float y = pts[3 * (size_t)i + 1];
            float z = pts[3 * (size_t)i + 2];
            atomicAdd(&hist[bin_of(x, y, z)], 1u);
        }
        return;
    }

    int plane = b >> 11;              // 2048 tiles per plane
    int s0    = (b & 2047) << 7;      // * 128 spatial base
    const float* src = in  + (size_t)plane * NCH * SP;
    _Float16*    dst = out + (size_t)plane * SP  * NCH;

    int tid = threadIdx.x;
    int r   = tid >> 4;               // 0..15
    int c4  = (tid & 15) << 2;        // 0,4,...,60

    v4f vv[8];
    #pragma unroll
    for (int it = 0; it < 8; ++it) {
        int ch = r + (it & 3) * 16;            // 0..63
        int sp = ((it >> 2) << 6) + c4;        // 0..124
        vv[it] = nt_load4(src + (size_t)ch * SP + s0 + sp);
    }
    #pragma unroll
    for (int it = 0; it < 8; ++it) {
        int ch = r + (it & 3) * 16;
        int sp = ((it >> 2) << 6) + c4;
        tile[ch][sp + 0] = vv[it][0];
        tile[ch][sp + 1] = vv[it][1];
        tile[ch][sp + 2] = vv[it][2];
        tile[ch][sp + 3] = vv[it][3];
    }
    __syncthreads();
    #pragma unroll
    for (int it = 0; it < 8; ++it) {
        int s = r + (it & 3) * 16 + ((it >> 2) << 6);   // 0..127
        h4 v;
        v[0] = (_Float16)tile[c4 + 0][s];
        v[1] = (_Float16)tile[c4 + 1][s];
        v[2] = (_Float16)tile[c4 + 2][s];
        v[3] = (_Float16)tile[c4 + 3][s];
        *(h4*)(dst + (size_t)(s0 + s) * NCH + c4) = v;   // cached: keep tp in L3
    }
}

// ---------------------------------------------------------------------------
// Kernel S2: exclusive prefix sum over 32768 bins (single block, 1024 thr)
// ---------------------------------------------------------------------------
__global__ __launch_bounds__(1024) void scan_kernel(
    const unsigned* __restrict__ hist, unsigned* __restrict__ offs)
{
    __shared__ unsigned partial[1024];
    int t = threadIdx.x;
    unsigned base = (unsigned)t * 32;
    unsigned local[32];
    unsigned s = 0;
    #pragma unroll
    for (int k = 0; k < 32; ++k) { local[k] = s; s += hist[base + k]; }
    partial[t] = s;
    __syncthreads();
    for (int d = 1; d < 1024; d <<= 1) {
        unsigned v = (t >= d) ? partial[t - d] : 0u;
        __syncthreads();
        partial[t] += v;
        __syncthreads();
    }
    unsigned chunk_excl = (t == 0) ? 0u : partial[t - 1];
    #pragma unroll
    for (int k = 0; k < 32; ++k) offs[base + k] = chunk_excl + local[k];
}

// ---------------------------------------------------------------------------
// Kernel S3: scatter (x,y,z,bits(idx)) as ONE aligned float4 per point into
// Morton-sorted order.
// ---------------------------------------------------------------------------
__global__ __launch_bounds__(256) void scatter_kernel(
    const float* __restrict__ pts, unsigned* __restrict__ offs,
    float* __restrict__ spts4, int npts)
{
    int i = blockIdx.x * 256 + threadIdx.x;
    if (i >= npts) return;
    float x = pts[3 * (size_t)i + 0];
    float y = pts[3 * (size_t)i + 1];
    float z = pts[3 * (size_t)i + 2];
    unsigned pos = atomicAdd(&offs[bin_of(x, y, z)], 1u);
    v4f v;
    v[0] = x; v[1] = y; v[2] = z; v[3] = __uint_as_float((unsigned)i);
    *(v4f*)(spts4 + 4 * (size_t)pos) = v;
}

// ---------------------------------------------------------------------------
// Kernel 2 (sorted): gather from fp16 texel-major planes in Morton order.
// 16 threads per point, 4 channels each = 8 B loads; texel = 128 B/16 lanes.
// fp16 tp = 100.7 MB -> L3-resident even against the 262 MB out stream.
// Weights + accumulation in fp32. NT stores for out; NT load for spts4.
// Chunked bijective XCD swizzle.
// ---------------------------------------------------------------------------
__global__ __launch_bounds__(256) void gather_sorted(
    const float* __restrict__ spts4,
    const _Float16* __restrict__ tp, float* __restrict__ out,
    int npts, int nblk)
{
    int cpx = nblk >> 3;                       // nblk % 8 == 0 by launch
    int b   = blockIdx.x;
    int swz = (b & 7) * cpx + (b >> 3);        // bijective chunked XCD swizzle
    int t   = swz * 256 + threadIdx.x;
    int j   = t >> 4;                          // sorted position
    if (j >= npts) return;
    int cg  = (t & 15) << 2;                   // channel offset 0..60

    v4f s = nt_load4(spts4 + 4 * (size_t)j);   // broadcast within group
    float px = s[0], py = s[1], pz = s[2];
    unsigned idx = __float_as_uint(s[3]);

    float us[3] = {px, px, py};
    float vs[3] = {py, pz, pz};

    v4f acc = {0.f, 0.f, 0.f, 0.f};

    #pragma unroll
    for (int pl = 0; pl < 3; ++pl) {
        float fx = fminf(fmaxf((us[pl] + 1.0f) * 0.5f * 511.0f, 0.0f), 511.0f);
        float fy = fminf(fmaxf((vs[pl] + 1.0f) * 0.5f * 511.0f, 0.0f), 511.0f);
        float x0f = floorf(fx), y0f = floorf(fy);
        int   x0  = (int)x0f,  y0  = (int)y0f;
        float wx  = fx - x0f,  wy  = fy - y0f;
        int   x1  = min(x0 + 1, RES - 1);
        int   y1  = min(y0 + 1, RES - 1);

        const _Float16* base = tp + (size_t)pl * SP * NCH;
        h4 a00 = *(const h4*)(base + ((size_t)(y0 * RES + x0) * NCH) + cg);
        h4 a01 = *(const h4*)(base + ((size_t)(y0 * RES + x1) * NCH) + cg);
        h4 a10 = *(const h4*)(base + ((size_t)(y1 * RES + x0) * NCH) + cg);
        h4 a11 = *(const h4*)(base + ((size_t)(y1 * RES + x1) * NCH) + cg);

        float w00 = (1.0f - wx) * (1.0f - wy);
        float w01 = wx * (1.0f - wy);
        float w10 = (1.0f - wx) * wy;
        float w11 = wx * wy;

        v4f v00 = {(float)a00[0], (float)a00[1], (float)a00[2], (float)a00[3]};
        v4f v01 = {(float)a01[0], (float)a01[1], (float)a01[2], (float)a01[3]};
        v4f v10 = {(float)a10[0], (float)a10[1], (float)a10[2], (float)a10[3]};
        v4f v11 = {(float)a11[0], (float)a11[1], (float)a11[2], (float)a11[3]};

        acc += w00 * v00 + w01 * v01 + w10 * v10 + w11 * v11;
    }

    nt_store4(out + (size_t)idx * NCH + cg, acc);
}

// ---------------------------------------------------------------------------
// Fallback tier: unsorted gather from fp16 texel-major planes.
// ---------------------------------------------------------------------------
__global__ __launch_bounds__(256) void gather_tp(
    const float* __restrict__ pts,
    const _Float16* __restrict__ tp,
    float* __restrict__ out, int npts)
{
    int t  = blockIdx.x * 256 + threadIdx.x;
    int pt = t >> 4;
    if (pt >= npts) return;
    int cg = (t & 15) << 2;

    float px = pts[3 * (size_t)pt + 0];
    float py = pts[3 * (size_t)pt + 1];
    float pz = pts[3 * (size_t)pt + 2];

    float us[3] = {px, px, py};
    float vs[3] = {py, pz, pz};

    v4f acc = {0.f, 0.f, 0.f, 0.f};

    #pragma unroll
    for (int pl = 0; pl < 3; ++pl) {
        float fx = fminf(fmaxf((us[pl] + 1.0f) * 0.5f * 511.0f, 0.0f), 511.0f);
        float fy = fminf(fmaxf((vs[pl] + 1.0f) * 0.5f * 511.0f, 0.0f), 511.0f);
        float x0f = floorf(fx), y0f = floorf(fy);
        int   x0  = (int)x0f,  y0  = (int)y0f;
        float wx  = fx - x0f,  wy  = fy - y0f;
        int   x1  = min(x0 + 1, RES - 1);
        int   y1  = min(y0 + 1, RES - 1);

        const _Float16* base = tp + (size_t)pl * SP * NCH;
        h4 a00 = *(const h4*)(base + ((size_t)(y0 * RES + x0) * NCH) + cg);
        h4 a01 = *(const h4*)(base + ((size_t)(y0 * RES + x1) * NCH) + cg);
        h4 a10 = *(const h4*)(base + ((size_t)(y1 * RES + x0) * NCH) + cg);
        h4 a11 = *(const h4*)(base + ((size_t)(y1 * RES + x1) * NCH) + cg);

        float w00 = (1.0f - wx) * (1.0f - wy);
        float w01 = wx * (1.0f - wy);
        float w10 = (1.0f - wx) * wy;
        float w11 = wx * wy;

        v4f v00 = {(float)a00[0], (float)a00[1], (float)a00[2], (float)a00[3]};
        v4f v01 = {(float)a01[0], (float)a01[1], (float)a01[2], (float)a01[3]};
        v4f v10 = {(float)a10[0], (float)a10[1], (float)a10[2], (float)a10[3]};
        v4f v11 = {(float)a11[0], (float)a11[1], (float)a11[2], (float)a11[3]};

        acc += w00 * v00 + w01 * v01 + w10 * v10 + w11 * v11;
    }

    *(v4f*)(out + (size_t)pt * NCH + cg) = acc;
}

// ---------------------------------------------------------------------------
// Last-resort fallback: direct gather from original (3, C, R, R) fp32 layout.
// ---------------------------------------------------------------------------
__global__ __launch_bounds__(256) void gather_direct(
    const float* __restrict__ pts,
    const float* __restrict__ planes,
    float* __restrict__ out, int npts)
{
    long t = (long)blockIdx.x * 256 + threadIdx.x;
    int pt = (int)(t >> 6);
    if (pt >= npts) return;
    int ch = (int)(t & 63);

    float px = pts[3 * (size_t)pt + 0];
    float py = pts[3 * (size_t)pt + 1];
    float pz = pts[3 * (size_t)pt + 2];
    float us[3] = {px, px, py};
    float vs[3] = {py, pz, pz};

    float acc = 0.0f;
    #pragma unroll
    for (int pl = 0; pl < 3; ++pl) {
        float fx = fminf(fmaxf((us[pl] + 1.0f) * 0.5f * 511.0f, 0.0f), 511.0f);
        float fy = fminf(fmaxf((vs[pl] + 1.0f) * 0.5f * 511.0f, 0.0f), 511.0f);
        float x0f = floorf(fx), y0f = floorf(fy);
        int   x0  = (int)x0f,  y0  = (int)y0f;
        float wx  = fx - x0f,  wy  = fy - y0f;
        int   x1  = min(x0 + 1, RES - 1);
        int   y1  = min(y0 + 1, RES - 1);

        const float* base = planes + (size_t)pl * NCH * SP + (size_t)ch * SP;
        float v00 = base[y0 * RES + x0];
        float v01 = base[y0 * RES + x1];
        float v10 = base[y1 * RES + x0];
        float v11 = base[y1 * RES + x1];

        acc += v00 * ((1.0f - wx) * (1.0f - wy))
             + v01 * (wx * (1.0f - wy))
             + v10 * ((1.0f - wx) * wy)
             + v11 * (wx * wy);
    }
    out[(size_t)pt * NCH + ch] = acc;
}

extern "C" void kernel_launch(void* const* d_in, const int* in_sizes, int n_in,
                              void* d_out, int out_size, void* d_ws, size_t ws_size,
                              hipStream_t stream)
{
    (void)n_in; (void)out_size;
    const float* pts    = (const float*)d_in[0];
    const float* planes = (const float*)d_in[1];
    float*       out    = (float*)d_out;
    int npts = in_sizes[0] / 3;

    // workspace layout (fp16 tp = 100.7 MB)
    size_t sz_tp     = (size_t)3 * NCH * SP * sizeof(_Float16);
    size_t off_spts  = sz_tp;                                      // 16B-aligned
    size_t sz_spts   = (size_t)npts * 4 * sizeof(float);           // float4/point
    size_t off_hist  = off_spts + sz_spts;
    size_t off_offs  = off_hist + (size_t)NBINS * sizeof(unsigned);
    size_t need_sort = off_offs + (size_t)NBINS * sizeof(unsigned);

    int nptblk = (npts + 255) / 256;

    if (ws_size >= need_sort) {
        _Float16* tp   = (_Float16*)d_ws;
        float*    sp4  = (float*)((char*)d_ws + off_spts);
        unsigned* hist = (unsigned*)((char*)d_ws + off_hist);
        unsigned* offs = (unsigned*)((char*)d_ws + off_offs);

        hipMemsetAsync(hist, 0, (size_t)NBINS * sizeof(unsigned), stream);
        transpose_hist<<<TRBLK + nptblk, 256, 0, stream>>>(
            planes, tp, pts, hist, npts);
        scan_kernel<<<1, 1024, 0, stream>>>(hist, offs);
        scatter_kernel<<<nptblk, 256, 0, stream>>>(pts, offs, sp4, npts);

        long nthr = (long)npts * 16;
        int  nblk = (int)((nthr + 255) / 256);
        nblk = (nblk + 7) & ~7;                 // multiple of 8 for bijective swizzle
        gather_sorted<<<nblk, 256, 0, stream>>>(sp4, tp, out, npts, nblk);
    } else if (ws_size >= sz_tp) {
        transpose_hist<<<TRBLK, 256, 0, stream>>>(
            planes, (_Float16*)d_ws, nullptr, nullptr, 0);
        long nthr = (long)npts * 16;
        gather_tp<<<(int)((nthr + 255) / 256), 256, 0, stream>>>(
            pts, (const _Float16*)d_ws, out, npts);
    } else {
        long nthr = (long)npts * 64;
        gather_direct<<<(int)((nthr + 255) / 256), 256, 0, stream>>>(
            pts, planes, out, npts);
    }
}

// Round 5
// 550.772 us; speedup vs baseline: 1.2576x; 1.1059x over previous
//
#include <hip/hip_runtime.h>

#define RES   512
#define NCH   64            // channels
#define SP    (RES * RES)   // 262144 texels per plane

// Morton binning for point sort (3D locality => locality in all 3 plane projections)
#define NBITS 5
#define NSIDE (1 << NBITS)           // 32 voxels per axis
#define NBINS (1 << (3 * NBITS))     // 32768 bins, ~32 pts/bin at 1M pts

#define TRBLK 3072                   // transpose blocks: 3 * (SP/256)

typedef float     v4f __attribute__((ext_vector_type(4)));
typedef _Float16  h4  __attribute__((ext_vector_type(4)));
typedef _Float16  h8  __attribute__((ext_vector_type(8)));

__device__ __forceinline__ v4f nt_load4(const float* p)
{
    return __builtin_nontemporal_load((const v4f*)p);
}
__device__ __forceinline__ void nt_store4(float* p, v4f v)
{
    __builtin_nontemporal_store(v, (v4f*)p);
}

// ---------------------------------------------------------------------------
// Morton helpers
// ---------------------------------------------------------------------------
__device__ __forceinline__ unsigned part1by2(unsigned v)
{
    v &= 0x3FF;
    v = (v | (v << 16)) & 0x030000FF;
    v = (v | (v <<  8)) & 0x0300F00F;
    v = (v | (v <<  4)) & 0x030C30C3;
    v = (v | (v <<  2)) & 0x09249249;
    return v;
}

__device__ __forceinline__ unsigned bin_of(float x, float y, float z)
{
    int ix = (int)((x + 1.0f) * 0.5f * (float)NSIDE);
    int iy = (int)((y + 1.0f) * 0.5f * (float)NSIDE);
    int iz = (int)((z + 1.0f) * 0.5f * (float)NSIDE);
    ix = min(max(ix, 0), NSIDE - 1);
    iy = min(max(iy, 0), NSIDE - 1);
    iz = min(max(iz, 0), NSIDE - 1);
    return part1by2((unsigned)ix) | (part1by2((unsigned)iy) << 1)
         | (part1by2((unsigned)iz) << 2);
}

// ---------------------------------------------------------------------------
// Kernel H: histogram of Morton bins (exposed ~18 us; must precede scan).
// ---------------------------------------------------------------------------
__global__ __launch_bounds__(256) void hist_kernel(
    const float* __restrict__ pts, unsigned* __restrict__ hist, int npts)
{
    int i = blockIdx.x * 256 + threadIdx.x;
    if (i >= npts) return;
    float x = pts[3 * (size_t)i + 0];
    float y = pts[3 * (size_t)i + 1];
    float z = pts[3 * (size_t)i + 2];
    atomicAdd(&hist[bin_of(x, y, z)], 1u);
}

// ---------------------------------------------------------------------------
// Kernel S2: exclusive prefix sum over 32768 bins (single block, 1024 thr)
// ---------------------------------------------------------------------------
__global__ __launch_bounds__(1024) void scan_kernel(
    const unsigned* __restrict__ hist, unsigned* __restrict__ offs)
{
    __shared__ unsigned partial[1024];
    int t = threadIdx.x;
    unsigned base = (unsigned)t * 32;
    unsigned local[32];
    unsigned s = 0;
    #pragma unroll
    for (int k = 0; k < 32; ++k) { local[k] = s; s += hist[base + k]; }
    partial[t] = s;
    __syncthreads();
    for (int d = 1; d < 1024; d <<= 1) {
        unsigned v = (t >= d) ? partial[t - d] : 0u;
        __syncthreads();
        partial[t] += v;
        __syncthreads();
    }
    unsigned chunk_excl = (t == 0) ? 0u : partial[t - 1];
    #pragma unroll
    for (int k = 0; k < 32; ++k) offs[base + k] = chunk_excl + local[k];
}

// ---------------------------------------------------------------------------
// Kernel 1 (fused, INTERLEAVED): even blocks scatter points into Morton order
// (co-runs with the transpose from dispatch, retires early -> hidden; R3's
// appended-tail mistake avoided); odd blocks transpose (3,C,R,R) fp32 ->
// (3,R*R,C) fp16.
//
// Transpose tile: 64ch x 256sp. Load: each wave-instruction reads ONE channel,
// 64 lanes x 16 B = 1 KB contiguous (R2/R4 issued 4x256B segments -> 2.1 TB/s;
// R3 actually issued 8x128B, worse, which is why its "1 KB" theory failed).
// LDS: fp16 texel-major [256][72] (36.9 KB, 4 blocks/CU), converted on load.
// Store phase: 8 texels x 128 B = 1 KB contiguous fp16 per wave-instruction.
// LDS op volume ~2 us/CU total -> bank imperfection irrelevant.
// ---------------------------------------------------------------------------
__global__ __launch_bounds__(256) void transpose_scatter(
    const float* __restrict__ in, _Float16* __restrict__ outp,
    const float* __restrict__ pts, unsigned* __restrict__ offs,
    float* __restrict__ spts4, int npts)
{
    __shared__ _Float16 tile[256][72];   // pitch 144 B: 16 B-aligned rows

    int b    = blockIdx.x;
    int id   = b >> 1;
    if ((b & 1) == 0) {
        // scatter half (ids cover ceil(npts/256) blocks; extras no-op)
        if (pts == nullptr) return;
        int i = id * 256 + threadIdx.x;
        if (i < npts) {
            float x = pts[3 * (size_t)i + 0];
            float y = pts[3 * (size_t)i + 1];
            float z = pts[3 * (size_t)i + 2];
            unsigned pos = atomicAdd(&offs[bin_of(x, y, z)], 1u);
            v4f v;
            v[0] = x; v[1] = y; v[2] = z; v[3] = __uint_as_float((unsigned)i);
            *(v4f*)(spts4 + 4 * (size_t)pos) = v;
        }
        return;
    }
    if (id >= TRBLK) return;

    int plane = id >> 10;             // 1024 tiles per plane
    int s0    = (id & 1023) << 8;     // * 256 spatial base
    const float* src = in   + (size_t)plane * NCH * SP;
    _Float16*    dst = outp + (size_t)plane * SP  * NCH;

    int w = threadIdx.x >> 6;         // wave 0..3 -> channels [w*16, w*16+16)
    int l = threadIdx.x & 63;

    #pragma unroll
    for (int g = 0; g < 4; ++g) {
        int c0 = w * 16 + g * 4;
        v4f v0 = nt_load4(src + (size_t)(c0 + 0) * SP + s0 + 4 * l);
        v4f v1 = nt_load4(src + (size_t)(c0 + 1) * SP + s0 + 4 * l);
        v4f v2 = nt_load4(src + (size_t)(c0 + 2) * SP + s0 + 4 * l);
        v4f v3 = nt_load4(src + (size_t)(c0 + 3) * SP + s0 + 4 * l);
        #pragma unroll
        for (int i = 0; i < 4; ++i) {
            h4 hv;
            hv[0] = (_Float16)v0[i];
            hv[1] = (_Float16)v1[i];
            hv[2] = (_Float16)v2[i];
            hv[3] = (_Float16)v3[i];
            *(h4*)&tile[4 * l + i][c0] = hv;
        }
    }
    __syncthreads();

    #pragma unroll
    for (int j = 0; j < 8; ++j) {
        int texel = w * 64 + j * 8 + (l >> 3);
        int oct   = (l & 7) << 3;
        h8 hv = *(const h8*)&tile[texel][oct];
        *(h8*)(dst + (size_t)(s0 + texel) * NCH + oct) = hv;
    }
}

// ---------------------------------------------------------------------------
// Kernel 2 (sorted): gather from fp16 texel-major planes in Morton order.
// 8 threads per point, 8 channels each (h8 = 16 B loads); texel = one full
// 128 B line. Halves waves/point, redundant address math, spts4 broadcasts
// vs the 16-lane scheme. Weights + accumulation fp32. NT out stores; NT spts
// load. Chunked bijective XCD swizzle.
// ---------------------------------------------------------------------------
__global__ __launch_bounds__(256) void gather_sorted(
    const float* __restrict__ spts4,
    const _Float16* __restrict__ tp, float* __restrict__ out,
    int npts, int nblk)
{
    int cpx = nblk >> 3;                       // nblk % 8 == 0 by launch
    int b   = blockIdx.x;
    int swz = (b & 7) * cpx + (b >> 3);        // bijective chunked XCD swizzle
    int t   = swz * 256 + threadIdx.x;
    int j   = t >> 3;                          // sorted position
    if (j >= npts) return;
    int cg  = (t & 7) << 3;                    // channel offset 0..56

    v4f s = nt_load4(spts4 + 4 * (size_t)j);   // broadcast within 8-lane group
    float px = s[0], py = s[1], pz = s[2];
    unsigned idx = __float_as_uint(s[3]);

    float us[3] = {px, px, py};
    float vs[3] = {py, pz, pz};

    v4f acc0 = {0.f, 0.f, 0.f, 0.f};
    v4f acc1 = {0.f, 0.f, 0.f, 0.f};

    #pragma unroll
    for (int pl = 0; pl < 3; ++pl) {
        float fx = fminf(fmaxf((us[pl] + 1.0f) * 0.5f * 511.0f, 0.0f), 511.0f);
        float fy = fminf(fmaxf((vs[pl] + 1.0f) * 0.5f * 511.0f, 0.0f), 511.0f);
        float x0f = floorf(fx), y0f = floorf(fy);
        int   x0  = (int)x0f,  y0  = (int)y0f;
        float wx  = fx - x0f,  wy  = fy - y0f;
        int   x1  = min(x0 + 1, RES - 1);
        int   y1  = min(y0 + 1, RES - 1);

        const _Float16* base = tp + (size_t)pl * SP * NCH;
        h8 a00 = *(const h8*)(base + ((size_t)(y0 * RES + x0) * NCH) + cg);
        h8 a01 = *(const h8*)(base + ((size_t)(y0 * RES + x1) * NCH) + cg);
        h8 a10 = *(const h8*)(base + ((size_t)(y1 * RES + x0) * NCH) + cg);
        h8 a11 = *(const h8*)(base + ((size_t)(y1 * RES + x1) * NCH) + cg);

        float w00 = (1.0f - wx) * (1.0f - wy);
        float w01 = wx * (1.0f - wy);
        float w10 = (1.0f - wx) * wy;
        float w11 = wx * wy;

        #pragma unroll
        for (int k = 0; k < 4; ++k) {
            acc0[k] += w00 * (float)a00[k] + w01 * (float)a01[k]
                     + w10 * (float)a10[k] + w11 * (float)a11[k];
            acc1[k] += w00 * (float)a00[k + 4] + w01 * (float)a01[k + 4]
                     + w10 * (float)a10[k + 4] + w11 * (float)a11[k + 4];
        }
    }

    nt_store4(out + (size_t)idx * NCH + cg,     acc0);
    nt_store4(out + (size_t)idx * NCH + cg + 4, acc1);
}

// ---------------------------------------------------------------------------
// Fallback tier: unsorted gather from fp16 texel-major planes.
// ---------------------------------------------------------------------------
__global__ __launch_bounds__(256) void gather_tp(
    const float* __restrict__ pts,
    const _Float16* __restrict__ tp,
    float* __restrict__ out, int npts)
{
    int t  = blockIdx.x * 256 + threadIdx.x;
    int pt = t >> 3;
    if (pt >= npts) return;
    int cg = (t & 7) << 3;

    float px = pts[3 * (size_t)pt + 0];
    float py = pts[3 * (size_t)pt + 1];
    float pz = pts[3 * (size_t)pt + 2];

    float us[3] = {px, px, py};
    float vs[3] = {py, pz, pz};

    v4f acc0 = {0.f, 0.f, 0.f, 0.f};
    v4f acc1 = {0.f, 0.f, 0.f, 0.f};

    #pragma unroll
    for (int pl = 0; pl < 3; ++pl) {
        float fx = fminf(fmaxf((us[pl] + 1.0f) * 0.5f * 511.0f, 0.0f), 511.0f);
        float fy = fminf(fmaxf((vs[pl] + 1.0f) * 0.5f * 511.0f, 0.0f), 511.0f);
        float x0f = floorf(fx), y0f = floorf(fy);
        int   x0  = (int)x0f,  y0  = (int)y0f;
        float wx  = fx - x0f,  wy  = fy - y0f;
        int   x1  = min(x0 + 1, RES - 1);
        int   y1  = min(y0 + 1, RES - 1);

        const _Float16* base = tp + (size_t)pl * SP * NCH;
        h8 a00 = *(const h8*)(base + ((size_t)(y0 * RES + x0) * NCH) + cg);
        h8 a01 = *(const h8*)(base + ((size_t)(y0 * RES + x1) * NCH) + cg);
        h8 a10 = *(const h8*)(base + ((size_t)(y1 * RES + x0) * NCH) + cg);
        h8 a11 = *(const h8*)(base + ((size_t)(y1 * RES + x1) * NCH) + cg);

        float w00 = (1.0f - wx) * (1.0f - wy);
        float w01 = wx * (1.0f - wy);
        float w10 = (1.0f - wx) * wy;
        float w11 = wx * wy;

        #pragma unroll
        for (int k = 0; k < 4; ++k) {
            acc0[k] += w00 * (float)a00[k] + w01 * (float)a01[k]
                     + w10 * (float)a10[k] + w11 * (float)a11[k];
            acc1[k] += w00 * (float)a00[k + 4] + w01 * (float)a01[k + 4]
                     + w10 * (float)a10[k + 4] + w11 * (float)a11[k + 4];
        }
    }

    *(v4f*)(out + (size_t)pt * NCH + cg)     = acc0;
    *(v4f*)(out + (size_t)pt * NCH + cg + 4) = acc1;
}

// ---------------------------------------------------------------------------
// Last-resort fallback: direct gather from original (3, C, R, R) fp32 layout.
// ---------------------------------------------------------------------------
__global__ __launch_bounds__(256) void gather_direct(
    const float* __restrict__ pts,
    const float* __restrict__ planes,
    float* __restrict__ out, int npts)
{
    long t = (long)blockIdx.x * 256 + threadIdx.x;
    int pt = (int)(t >> 6);
    if (pt >= npts) return;
    int ch = (int)(t & 63);

    float px = pts[3 * (size_t)pt + 0];
    float py = pts[3 * (size_t)pt + 1];
    float pz = pts[3 * (size_t)pt + 2];
    float us[3] = {px, px, py};
    float vs[3] = {py, pz, pz};

    float acc = 0.0f;
    #pragma unroll
    for (int pl = 0; pl < 3; ++pl) {
        float fx = fminf(fmaxf((us[pl] + 1.0f) * 0.5f * 511.0f, 0.0f), 511.0f);
        float fy = fminf(fmaxf((vs[pl] + 1.0f) * 0.5f * 511.0f, 0.0f), 511.0f);
        float x0f = floorf(fx), y0f = floorf(fy);
        int   x0  = (int)x0f,  y0  = (int)y0f;
        float wx  = fx - x0f,  wy  = fy - y0f;
        int   x1  = min(x0 + 1, RES - 1);
        int   y1  = min(y0 + 1, RES - 1);

        const float* base = planes + (size_t)pl * NCH * SP + (size_t)ch * SP;
        float v00 = base[y0 * RES + x0];
        float v01 = base[y0 * RES + x1];
        float v10 = base[y1 * RES + x0];
        float v11 = base[y1 * RES + x1];

        acc += v00 * ((1.0f - wx) * (1.0f - wy))
             + v01 * (wx * (1.0f - wy))
             + v10 * ((1.0f - wx) * wy)
             + v11 * (wx * wy);
    }
    out[(size_t)pt * NCH + ch] = acc;
}

extern "C" void kernel_launch(void* const* d_in, const int* in_sizes, int n_in,
                              void* d_out, int out_size, void* d_ws, size_t ws_size,
                              hipStream_t stream)
{
    (void)n_in; (void)out_size;
    const float* pts    = (const float*)d_in[0];
    const float* planes = (const float*)d_in[1];
    float*       out    = (float*)d_out;
    int npts = in_sizes[0] / 3;

    // workspace layout (fp16 tp = 100.7 MB)
    size_t sz_tp     = (size_t)3 * NCH * SP * sizeof(_Float16);
    size_t off_spts  = sz_tp;                                      // 16B-aligned
    size_t sz_spts   = (size_t)npts * 4 * sizeof(float);           // float4/point
    size_t off_hist  = off_spts + sz_spts;
    size_t off_offs  = off_hist + (size_t)NBINS * sizeof(unsigned);
    size_t need_sort = off_offs + (size_t)NBINS * sizeof(unsigned);

    int nptblk = (npts + 255) / 256;

    if (ws_size >= need_sort) {
        _Float16* tp   = (_Float16*)d_ws;
        float*    sp4  = (float*)((char*)d_ws + off_spts);
        unsigned* hist = (unsigned*)((char*)d_ws + off_hist);
        unsigned* offs = (unsigned*)((char*)d_ws + off_offs);

        hipMemsetAsync(hist, 0, (size_t)NBINS * sizeof(unsigned), stream);
        hist_kernel<<<nptblk, 256, 0, stream>>>(pts, hist, npts);
        scan_kernel<<<1, 1024, 0, stream>>>(hist, offs);

        // interleaved: even blocks scatter, odd blocks transpose
        int half = (nptblk > TRBLK) ? nptblk : TRBLK;
        transpose_scatter<<<2 * half, 256, 0, stream>>>(
            planes, tp, pts, offs, sp4, npts);

        long nthr = (long)npts * 8;
        int  nblk = (int)((nthr + 255) / 256);
        nblk = (nblk + 7) & ~7;                 // multiple of 8 for bijective swizzle
        gather_sorted<<<nblk, 256, 0, stream>>>(sp4, tp, out, npts, nblk);
    } else if (ws_size >= sz_tp) {
        transpose_scatter<<<2 * TRBLK, 256, 0, stream>>>(
            planes, (_Float16*)d_ws, nullptr, nullptr, nullptr, 0);
        long nthr = (long)npts * 8;
        gather_tp<<<(int)((nthr + 255) / 256), 256, 0, stream>>>(
            pts, (const _Float16*)d_ws, out, npts);
    } else {
        long nthr = (long)npts * 64;
        gather_direct<<<(int)((nthr + 255) / 256), 256, 0, stream>>>(
            pts, planes, out, npts);
    }
}